// Round 3
// baseline (49.981 us; speedup 1.0000x reference)
//
#include <hip/hip_runtime.h>
#include <hip/hip_bf16.h>

#define S_ 1024
#define E_ 768
#define H_ 12

typedef __bf16  bf16x8 __attribute__((ext_vector_type(8)));
typedef float   f32x4  __attribute__((ext_vector_type(4)));
typedef unsigned short u16x8 __attribute__((ext_vector_type(8)));
typedef unsigned short u16x4 __attribute__((ext_vector_type(4)));

__device__ __forceinline__ unsigned short f2bf(float f) {
    union { float f; unsigned u; } a; a.f = f;
    unsigned u = a.u;
    u += 0x7FFFu + ((u >> 16) & 1u);   // RNE
    return (unsigned short)(u >> 16);
}

__device__ __forceinline__ u16x8 pack8(float4 a, float4 b, float w) {
    u16x8 o;
    o[0] = f2bf(a.x * w); o[1] = f2bf(a.y * w); o[2] = f2bf(a.z * w); o[3] = f2bf(a.w * w);
    o[4] = f2bf(b.x * w); o[5] = f2bf(b.y * w); o[6] = f2bf(b.z * w); o[7] = f2bf(b.w * w);
    return o;
}

// LDS tile layout: R rows x 64 bf16 (128B/row, 8x16B chunks).
// Physical chunk (row, cb) holds global chunk (row, cb ^ (row&7)).
__device__ __forceinline__ bf16x8 ld_frag(const char* lbase, int row, int kk, int lane) {
    int cbyte = (kk * 64 + ((lane >> 4) * 16)) ^ ((row & 7) << 4);
    return *(const bf16x8*)(lbase + row * 128 + cbyte);
}

// ---------------- proj: P[m,n] = sum_k X[m,k]*W[n,k]*scale_n + bias_n, bf16 out ----------------
// 64x64 tile, 2x2 waves of 32x32; X and W both reg-staged fp32->bf16 into dbuf LDS; 2-phase.
__global__ __launch_bounds__(256) void proj_kernel(
    const float* __restrict__ q_in, const float* __restrict__ k_in,
    const float* __restrict__ Wq, const float* __restrict__ Wk,
    const float* __restrict__ bq, const float* __restrict__ bk,
    const float* __restrict__ lin_w,
    unsigned short* __restrict__ qs, unsigned short* __restrict__ kp)
{
    __shared__ char lds[32768];   // Xb0 Xb1 Wb0 Wb1, 8KB each

    const float* X    = blockIdx.z ? k_in : q_in;
    const float* W    = blockIdx.z ? Wk   : Wq;
    const float* bias = blockIdx.z ? bk   : bq;
    unsigned short* P = blockIdx.z ? kp   : qs;
    const float invs = 0.35355339059327373f; // 1/sqrt(8)

    int tid = threadIdx.x, lane = tid & 63, wid = tid >> 6;
    int wn = wid >> 1, wm = wid & 1;
    int tm = blockIdx.y * 64, tn = blockIdx.x * 64;

    // staging coords: thread covers chunks c0=tid (rows 0..31) and c1=256+tid (rows 32..63)
    int c0 = tid,        r0 = c0 >> 3, g0 = ((c0 & 7) ^ (r0 & 7)) * 8;
    int c1 = 256 + tid,  r1 = c1 >> 3, g1 = ((c1 & 7) ^ (r1 & 7)) * 8;
    float sw0 = 1.0f, sw1 = 1.0f;                 // W row scale (q side folds lin_w)
    if (blockIdx.z == 0) { sw0 = lin_w[r0 >> 3] * invs; sw1 = lin_w[r1 >> 3] * invs; }

    const float* Xg = X + (size_t)tm * E_;
    const float* Wg = W + (size_t)tn * E_;

    float4 xv0, xv1, xv2, xv3, wv0, wv1, wv2, wv3;
#define LOADXW(kb) { \
    const float* xs0 = Xg + r0 * E_ + (kb) + g0; xv0 = *(const float4*)xs0; xv1 = *(const float4*)(xs0 + 4); \
    const float* xs1 = Xg + r1 * E_ + (kb) + g1; xv2 = *(const float4*)xs1; xv3 = *(const float4*)(xs1 + 4); \
    const float* ws0 = Wg + r0 * E_ + (kb) + g0; wv0 = *(const float4*)ws0; wv1 = *(const float4*)(ws0 + 4); \
    const float* ws1 = Wg + r1 * E_ + (kb) + g1; wv2 = *(const float4*)ws1; wv3 = *(const float4*)(ws1 + 4); }
#define WRITEXW(buf) { \
    char* xb = lds + (buf) * 8192; \
    *(u16x8*)(xb + c0 * 16) = pack8(xv0, xv1, 1.0f); \
    *(u16x8*)(xb + c1 * 16) = pack8(xv2, xv3, 1.0f); \
    char* wb = lds + 16384 + (buf) * 8192; \
    *(u16x8*)(wb + c0 * 16) = pack8(wv0, wv1, sw0); \
    *(u16x8*)(wb + c1 * 16) = pack8(wv2, wv3, sw1); }

    // accumulators: acc[nj][mi]; D rows = W-dim (n), cols = X-dim (m)  [swapped operands]
    f32x4 acc[2][2];
#pragma unroll
    for (int nj = 0; nj < 2; ++nj) {
        int n0 = tn + wn * 32 + nj * 16 + ((lane >> 4) << 2);
        float4 b4 = *(const float4*)(bias + n0);
        float w = (blockIdx.z == 0) ? lin_w[(n0 & 63) >> 3] * invs : 1.0f;
#pragma unroll
        for (int mi = 0; mi < 2; ++mi)
            acc[nj][mi] = f32x4{b4.x * w, b4.y * w, b4.z * w, b4.w * w};
    }

#define COMPSTEP(buf) { \
    const char* Xc = lds + (buf) * 8192; \
    const char* Wc = lds + 16384 + (buf) * 8192; \
    _Pragma("unroll") \
    for (int kk = 0; kk < 2; ++kk) { \
        bf16x8 a0 = ld_frag(Wc, wn * 32 + (lane & 15), kk, lane); \
        bf16x8 a1 = ld_frag(Wc, wn * 32 + 16 + (lane & 15), kk, lane); \
        bf16x8 b0 = ld_frag(Xc, wm * 32 + (lane & 15), kk, lane); \
        bf16x8 b1 = ld_frag(Xc, wm * 32 + 16 + (lane & 15), kk, lane); \
        acc[0][0] = __builtin_amdgcn_mfma_f32_16x16x32_bf16(a0, b0, acc[0][0], 0, 0, 0); \
        acc[0][1] = __builtin_amdgcn_mfma_f32_16x16x32_bf16(a0, b1, acc[0][1], 0, 0, 0); \
        acc[1][0] = __builtin_amdgcn_mfma_f32_16x16x32_bf16(a1, b0, acc[1][0], 0, 0, 0); \
        acc[1][1] = __builtin_amdgcn_mfma_f32_16x16x32_bf16(a1, b1, acc[1][1], 0, 0, 0); \
    } }

    // prologue
    LOADXW(0);
    WRITEXW(0);
    __syncthreads();
    int cur = 0;
#pragma unroll 2
    for (int t = 0; t < 11; ++t) {
        LOADXW((t + 1) * 64);      // prefetch next tile (overlaps compute)
        COMPSTEP(cur);
        WRITEXW(cur ^ 1);          // write-late after compute
        __syncthreads();
        cur ^= 1;
    }
    COMPSTEP(cur);

    // store: thread holds 4 consecutive n per acc -> packed 8B bf16 stores
#pragma unroll
    for (int nj = 0; nj < 2; ++nj)
#pragma unroll
        for (int mi = 0; mi < 2; ++mi) {
            int n0 = tn + wn * 32 + nj * 16 + ((lane >> 4) << 2);
            int m  = tm + wm * 32 + mi * 16 + (lane & 15);
            u16x4 pk;
            pk[0] = f2bf(acc[nj][mi][0]); pk[1] = f2bf(acc[nj][mi][1]);
            pk[2] = f2bf(acc[nj][mi][2]); pk[3] = f2bf(acc[nj][mi][3]);
            *(u16x4*)(P + (size_t)m * E_ + n0) = pk;
        }
#undef LOADXW
#undef WRITEXW
#undef COMPSTEP
}

// ---------------- scores: per (b,h): out[i,j] = qs_i . kp_j + lin_b, fp32 out ----------------
// Block: 128 i x 256 j (two 128-j subtiles). Q in registers; K dbuf LDS via global_load_lds.
// Swapped operands: A=K-frag (j -> D rows), B=Q-frag (i -> D cols) => dwordx4 stores along j.
__global__ __launch_bounds__(256) void scores_kernel(
    const unsigned short* __restrict__ qs, const unsigned short* __restrict__ kp,
    const float* __restrict__ lin_b, float* __restrict__ out)
{
    __shared__ char lds[32768];   // Kb0, Kb1: 16KB each (128 rows x 64 bf16)

    int z = blockIdx.z, b = z / H_, h = z - b * H_;
    int tid = threadIdx.x, lane = tid & 63, wid = tid >> 6;
    int wj = wid >> 1, wi = wid & 1;
    int ti = blockIdx.y * 128, tj = blockIdx.x * 256;

    const unsigned short* Qg = qs + (size_t)(b * S_) * E_ + h * 64;
    const unsigned short* Kg = kp + (size_t)(b * S_) * E_ + h * 64;

    // stage K subtile (128 rows x 64) swizzled via global_load_lds
#define STAGEK(jbase, buf) { \
    char* lb = lds + (buf) * 16384; \
    _Pragma("unroll") \
    for (int pass = 0; pass < 4; ++pass) { \
        int c = pass * 256 + tid; \
        int row = c >> 3, cbg = (c & 7) ^ (row & 7); \
        __builtin_amdgcn_global_load_lds( \
            (const __attribute__((address_space(1))) void*)(Kg + (size_t)((jbase) + row) * E_ + cbg * 8), \
            (__attribute__((address_space(3))) void*)(lb + c * 16), 16, 0, 0); \
    } }

    // Q fragments direct to registers: [kk][ni]
    bf16x8 qf[2][4];
    int qrow = ti + wi * 64 + (lane & 15);
#pragma unroll
    for (int ni = 0; ni < 4; ++ni)
#pragma unroll
        for (int kk = 0; kk < 2; ++kk)
            qf[kk][ni] = *(const bf16x8*)(Qg + (size_t)(qrow + ni * 16) * E_ + kk * 32 + ((lane >> 4) * 8));

    float lb0 = lin_b[0];
    float* O = out + ((size_t)z << 20);

    STAGEK(tj, 0);
    __syncthreads();                       // Kb0 ready
    STAGEK(tj + 128, 1);                   // prefetch second subtile

#pragma unroll
    for (int sub = 0; sub < 2; ++sub) {
        f32x4 acc[4][4];
#pragma unroll
        for (int mj = 0; mj < 4; ++mj)
#pragma unroll
            for (int ni = 0; ni < 4; ++ni) acc[mj][ni] = f32x4{lb0, lb0, lb0, lb0};

        const char* Kc = lds + sub * 16384;
#pragma unroll
        for (int kk = 0; kk < 2; ++kk) {
            bf16x8 a[4];
#pragma unroll
            for (int mj = 0; mj < 4; ++mj) a[mj] = ld_frag(Kc, wj * 64 + mj * 16 + (lane & 15), kk, lane);
#pragma unroll
            for (int mj = 0; mj < 4; ++mj)
#pragma unroll
                for (int ni = 0; ni < 4; ++ni)
                    acc[mj][ni] = __builtin_amdgcn_mfma_f32_16x16x32_bf16(a[mj], qf[kk][ni], acc[mj][ni], 0, 0, 0);
        }

#pragma unroll
        for (int mj = 0; mj < 4; ++mj)
#pragma unroll
            for (int ni = 0; ni < 4; ++ni) {
                int i  = ti + wi * 64 + ni * 16 + (lane & 15);
                int j0 = tj + sub * 128 + wj * 64 + mj * 16 + ((lane >> 4) << 2);
                *(float4*)(O + (size_t)i * S_ + j0) = (float4){acc[mj][ni][0], acc[mj][ni][1], acc[mj][ni][2], acc[mj][ni][3]};
            }

        if (sub == 0) __syncthreads();     // drain Kb1 stage loads
    }
#undef STAGEK
}

extern "C" void kernel_launch(void* const* d_in, const int* in_sizes, int n_in,
                              void* d_out, int out_size, void* d_ws, size_t ws_size,
                              hipStream_t stream)
{
    const float* k_in  = (const float*)d_in[0];
    const float* q_in  = (const float*)d_in[1];
    const float* Wq_w  = (const float*)d_in[2];
    const float* Wq_b  = (const float*)d_in[3];
    const float* Wk_w  = (const float*)d_in[4];
    const float* Wk_b  = (const float*)d_in[5];
    const float* lin_w = (const float*)d_in[6];
    const float* lin_b = (const float*)d_in[7];
    float* out = (float*)d_out;

    char* ws = (char*)d_ws;
    unsigned short* qsb = (unsigned short*)(ws + 0);
    unsigned short* kpb = (unsigned short*)(ws + 3145728);

    // 1) projections (weights cast + lin_w fold done in-kernel): qs=(q@Wq^T+bq)*w ; kp=k@Wk^T+bk
    proj_kernel<<<dim3(12, 32, 2), dim3(256), 0, stream>>>(q_in, k_in, Wq_w, Wk_w, Wq_b, Wk_b, lin_w, qsb, kpb);
    // 2) scores: out[b,h] = qs_h @ kp_h^T + lin_b  (fp32, 96MB, dwordx4 stores)
    scores_kernel<<<dim3(4, 8, 24), dim3(256), 0, stream>>>(qsb, kpb, lin_b, out);
}